// Round 3
// baseline (1479.641 us; speedup 1.0000x reference)
//
#include <hip/hip_runtime.h>

// LSTM: B=256, T=512, I=256, H=128 (4H=512 gates), then MLP 128->64->32->4.
//   gemm_gx_kernel : fp32 tiled GEMM for gx = x @ W_ih^T + bias (unchanged this round)
//   lstm_mfma_kernel : MFMA recurrence. 16 blocks x 512 thr (8 waves), 16 batch rows
//       per block. Per step: gates[512x16] = W_hh[512x128] @ h^T[128x16] via
//       mfma_f32_16x16x32_bf16. A = W_hh (STATIC -> registers, loaded once).
//       B = h (bf16, LDS, double-buffered, padded rows). Wave w owns gate-tiles
//       {w,8+w,16+w,24+w} -> i/f/g/o for j in [16w,16w+16) => c-update is in-lane,
//       no shuffles. One barrier per step. acc init = gx (prefetched float4).
//   head_kernel : tiny MLP per row.

#define TC    64
#define NCHUNK 8
#define BATCH 256
#define TSEQ  512
#define ISZ   256
#define HSZ   128
#define G4    512
#define RB    16                 // batch rows per recurrence block
#define HROW  136                // LDS row stride in shorts (272 B): 2-way alias only

typedef __attribute__((ext_vector_type(8))) short short8;
typedef __attribute__((ext_vector_type(4))) short shortx4;
typedef __attribute__((ext_vector_type(4))) float f32x4;

__device__ __forceinline__ float sigmoidf_(float x) {
    return 1.0f / (1.0f + __expf(-x));
}
__device__ __forceinline__ float tanhf_(float x) {
    float e = __expf(2.0f * x);          // saturates correctly for large |x|
    return 1.0f - 2.0f / (e + 1.0f);
}
__device__ __forceinline__ void fma4(float& a, const float4& w, const float4& h) {
    a += w.x * h.x; a += w.y * h.y; a += w.z * h.z; a += w.w * h.w;
}
__device__ __forceinline__ short f2bf(float x) {          // fp32 -> bf16 RNE
    union { float f; unsigned u; } v; v.f = x;
    unsigned r = v.u + 0x7fffu + ((v.u >> 16) & 1u);
    return (short)(r >> 16);
}

// ---------------------------------------------------------------------------
// gx GEMM: M = TC*256 rows (m = t_l*256 + b), N = 512, K = 256, fp32.
__global__ __launch_bounds__(256, 2) void gemm_gx_kernel(
    const float* __restrict__ x, const float* __restrict__ Wih,
    const float* __restrict__ bih, const float* __restrict__ bhh,
    float* __restrict__ gx, int t0)
{
    __shared__ __align__(16) float As[128 * 36];
    __shared__ __align__(16) float Bs[128 * 36];
    const int tid   = threadIdx.x;
    const int mtile = blockIdx.x;
    const int ntile = blockIdx.y;
    const int tl = mtile >> 1;
    const int b0 = (mtile & 1) * 128;
    const int n0 = ntile * 128;
    const int tx = tid & 15;
    const int ty = tid >> 4;

    float acc[8][8];
#pragma unroll
    for (int i = 0; i < 8; ++i)
#pragma unroll
        for (int j = 0; j < 8; ++j) acc[i][j] = 0.0f;

    const int sf = tid & 7;
    const int sr = tid >> 3;

    for (int ks = 0; ks < ISZ; ks += 32) {
#pragma unroll
        for (int u = 0; u < 4; ++u) {
            const int r = sr + u * 32;
            const float4 va = *(const float4*)(
                x + ((size_t)(b0 + r) * TSEQ + (size_t)(t0 + tl)) * ISZ + ks + sf * 4);
            *(float4*)(&As[r * 36 + sf * 4]) = va;
            const float4 vb = *(const float4*)(
                Wih + (size_t)(n0 + r) * ISZ + ks + sf * 4);
            *(float4*)(&Bs[r * 36 + sf * 4]) = vb;
        }
        __syncthreads();
#pragma unroll
        for (int kq = 0; kq < 8; ++kq) {
            float4 av[8], bv[8];
#pragma unroll
            for (int i = 0; i < 8; ++i)
                av[i] = *(const float4*)(&As[(ty * 8 + i) * 36 + kq * 4]);
#pragma unroll
            for (int j = 0; j < 8; ++j)
                bv[j] = *(const float4*)(&Bs[(tx + 16 * j) * 36 + kq * 4]);
#pragma unroll
            for (int i = 0; i < 8; ++i)
#pragma unroll
                for (int j = 0; j < 8; ++j)
                    fma4(acc[i][j], av[i], bv[j]);
        }
        __syncthreads();
    }

    const int m0 = mtile * 128;
#pragma unroll
    for (int j = 0; j < 8; ++j) {
        const int n = n0 + tx + 16 * j;
        const float bias = bih[n] + bhh[n];
#pragma unroll
        for (int i = 0; i < 8; ++i) {
            const int r = ty * 8 + i;
            gx[(size_t)(m0 + r) * G4 + n] = acc[i][j] + bias;
        }
    }
}

// ---------------------------------------------------------------------------
// MFMA recurrence. Grid = 16 blocks (16 batch rows each), 512 threads = 8 waves.
// D[m][n] (16x16): m = gate-in-tile = 4*quad + reg, n = batch = lane&15.
// A[m][k]: m = lane&15 (gate-in-tile), k = quad*8 + elem.  (static W_hh, registers)
// B[k][n]: n = lane&15 (batch), k = quad*8 + elem.         (h from LDS, b128 reads)
__global__ __launch_bounds__(512, 2) void lstm_mfma_kernel(
    const float* __restrict__ gx, const float* __restrict__ Whh,
    float* __restrict__ hc, int first)
{
    __shared__ __align__(16) short h_lds[2 * RB * HROW];   // double-buffered h (bf16)

    const int b0   = blockIdx.x * RB;
    const int tid  = threadIdx.x;
    const int w    = tid >> 6;           // wave 0..7
    const int lane = tid & 63;
    const int n    = lane & 15;          // batch col / A gate-row-in-tile
    const int quad = lane >> 4;          // 0..3

    // ---- static A-frags: W_hh rows for gate-tiles {w, 8+w, 16+w, 24+w} ----
    // A[g][ks]: W_hh[128g + 16w + n][32*ks + 8*quad + i], i=0..7, as bf16.
    short8 Af[4][4];
#pragma unroll
    for (int g = 0; g < 4; ++g) {
        const float* row = Whh + (size_t)(128 * g + 16 * w + n) * HSZ + 8 * quad;
#pragma unroll
        for (int ks = 0; ks < 4; ++ks) {
#pragma unroll
            for (int i = 0; i < 8; ++i)
                Af[g][ks][i] = f2bf(row[32 * ks + i]);
        }
    }

    // ---- init c (registers) and h (LDS buffer 0, bf16) ----
    const int j0 = 16 * w + 4 * quad;    // this lane's 4 hidden units j0..j0+3
    float c4[4] = {0.f, 0.f, 0.f, 0.f};
    {
        float4 hv = {0.f, 0.f, 0.f, 0.f};
        if (!first) {
            hv = *(const float4*)(hc + (size_t)(b0 + n) * HSZ + j0);
            const float4 cv = *(const float4*)(hc + (size_t)BATCH * HSZ +
                                               (size_t)(b0 + n) * HSZ + j0);
            c4[0] = cv.x; c4[1] = cv.y; c4[2] = cv.z; c4[3] = cv.w;
        }
        shortx4 hp = { f2bf(hv.x), f2bf(hv.y), f2bf(hv.z), f2bf(hv.w) };
        *(shortx4*)(&h_lds[n * HROW + j0]) = hp;
    }

    // gx pointers: lane's 4 gates per type g: gate = 128g + j0 (+reg)
    const float* gxp = gx + (size_t)(b0 + n) * G4 + j0;
    float4 gxf[4];
#pragma unroll
    for (int g = 0; g < 4; ++g) gxf[g] = *(const float4*)(gxp + 128 * g);

    __syncthreads();

    float hn[4] = {0.f, 0.f, 0.f, 0.f};

    for (int t = 0; t < TC; ++t) {
        const short* hb_r = h_lds + (t & 1) * (RB * HROW);
        short*       hb_w = h_lds + ((t + 1) & 1) * (RB * HROW);

        // B-frags: h[b=n][32*ks + 8*quad + i]
        short8 Bf[4];
#pragma unroll
        for (int ks = 0; ks < 4; ++ks)
            Bf[ks] = *(const short8*)(&hb_r[n * HROW + 32 * ks + 8 * quad]);

        // acc init = gx (x-part + biases), D reg r <-> gate row 4*quad + r
        f32x4 acc[4];
#pragma unroll
        for (int g = 0; g < 4; ++g) {
            acc[g][0] = gxf[g].x; acc[g][1] = gxf[g].y;
            acc[g][2] = gxf[g].z; acc[g][3] = gxf[g].w;
        }

        // prefetch next step's gx
        if (t + 1 < TC) {
            const float* p = gxp + (size_t)(t + 1) * BATCH * G4;
#pragma unroll
            for (int g = 0; g < 4; ++g) gxf[g] = *(const float4*)(p + 128 * g);
        }

        // 16 MFMAs: 4 independent chains (one per gate type)
#pragma unroll
        for (int ks = 0; ks < 4; ++ks) {
#pragma unroll
            for (int g = 0; g < 4; ++g)
                acc[g] = __builtin_amdgcn_mfma_f32_16x16x32_bf16(
                    Af[g][ks], Bf[ks], acc[g], 0, 0, 0);
        }

        // activations + state update: all in-lane. reg r -> j = j0 + r, batch n.
#pragma unroll
        for (int r = 0; r < 4; ++r) {
            const float ig = sigmoidf_(acc[0][r]);
            const float fg = sigmoidf_(acc[1][r]);
            const float gg = tanhf_(acc[2][r]);
            const float og = sigmoidf_(acc[3][r]);
            c4[r] = fg * c4[r] + ig * gg;
            hn[r] = og * tanhf_(c4[r]);
        }
        shortx4 hp = { f2bf(hn[0]), f2bf(hn[1]), f2bf(hn[2]), f2bf(hn[3]) };
        *(shortx4*)(&hb_w[n * HROW + j0]) = hp;

        __syncthreads();   // writes to hb_w visible before next step's reads
    }

    // write back h (fp32, from last step's pre-round values) and c
    float4 ho = { hn[0], hn[1], hn[2], hn[3] };
    float4 co = { c4[0], c4[1], c4[2], c4[3] };
    *(float4*)(hc + (size_t)(b0 + n) * HSZ + j0) = ho;
    *(float4*)(hc + (size_t)BATCH * HSZ + (size_t)(b0 + n) * HSZ + j0) = co;
}

// ---------------------------------------------------------------------------
// MLP head: one block (64 threads) per batch row.
__global__ __launch_bounds__(64) void head_kernel(
    const float* __restrict__ hc,
    const float* __restrict__ W1, const float* __restrict__ b1,
    const float* __restrict__ W2, const float* __restrict__ b2,
    const float* __restrict__ W3, const float* __restrict__ b3,
    float* __restrict__ out)
{
    __shared__ float hs[HSZ];
    __shared__ float o1[64];
    __shared__ float o2[32];
    const int bidx = blockIdx.x;
    const int t = threadIdx.x;
    hs[t]      = hc[bidx * HSZ + t];
    hs[t + 64] = hc[bidx * HSZ + t + 64];
    __syncthreads();
    {
        float a = b1[t];
#pragma unroll 8
        for (int k = 0; k < HSZ; ++k) a += W1[t * HSZ + k] * hs[k];
        o1[t] = fmaxf(a, 0.0f);
    }
    __syncthreads();
    if (t < 32) {
        float a = b2[t];
#pragma unroll 8
        for (int k = 0; k < 64; ++k) a += W2[t * 64 + k] * o1[k];
        o2[t] = fmaxf(a, 0.0f);
    }
    __syncthreads();
    if (t < 4) {
        float a = b3[t];
#pragma unroll
        for (int k = 0; k < 32; ++k) a += W3[t * 32 + k] * o2[k];
        out[bidx * 4 + t] = a;
    }
}

// ---------------------------------------------------------------------------
extern "C" void kernel_launch(void* const* d_in, const int* in_sizes, int n_in,
                              void* d_out, int out_size, void* d_ws, size_t ws_size,
                              hipStream_t stream) {
    const float* x   = (const float*)d_in[0];
    const float* Wih = (const float*)d_in[1];
    const float* Whh = (const float*)d_in[2];
    const float* bih = (const float*)d_in[3];
    const float* bhh = (const float*)d_in[4];
    const float* W1  = (const float*)d_in[5];
    const float* b1  = (const float*)d_in[6];
    const float* W2  = (const float*)d_in[7];
    const float* b2  = (const float*)d_in[8];
    const float* W3  = (const float*)d_in[9];
    const float* b3  = (const float*)d_in[10];
    float* out = (float*)d_out;

    float* gx = (float*)d_ws;                          // TC*256*512 floats = 33.5 MB
    float* hc = gx + (size_t)TC * BATCH * G4;          // h then c: 2 * 256*128 floats

    for (int cidx = 0; cidx < NCHUNK; ++cidx) {
        gemm_gx_kernel<<<dim3(128, 4), 256, 0, stream>>>(x, Wih, bih, bhh, gx, cidx * TC);
        lstm_mfma_kernel<<<dim3(BATCH / RB), 512, 0, stream>>>(gx, Whh, hc, cidx == 0);
    }
    head_kernel<<<dim3(BATCH), 64, 0, stream>>>(hc, W1, b1, W2, b2, W3, b3, out);
}

// Round 4
// 1151.211 us; speedup vs baseline: 1.2853x; 1.2853x over previous
//
#include <hip/hip_runtime.h>

// LSTM: B=256, T=512, I=256, H=128 (4H=512 gates), then MLP 128->64->32->4.
//   gemm_gx_kernel : bf16 MFMA GEMM, gx = x @ W_ih^T + bias, writes gx in bf16
//                    PERMUTED fragment layout (direct acc-init for recurrence).
//   lstm_mfma_kernel : 64 blocks (RB=4 batch rows each) x 512 thr (8 waves).
//       gates[512x16] = W_hh @ h^T per step via mfma_16x16x32_bf16; W_hh static in
//       VGPRs; h double-buffered in LDS; gx prefetched depth-2 with RAW s_barrier
//       (lgkmcnt only -- global loads stay in flight across the barrier).
//   head_kernel : tiny MLP per row.
// TC=128, NCHUNK=4: workspace = 33.55 MB gx(bf16) + 256 KB hc (same as round 1).

#define TC       128
#define NCHUNK   4
#define BATCH    256
#define TSEQ     512
#define ISZ      256
#define HSZ      128
#define G4       512
#define RB       4
#define NBLK     (BATCH / RB)
#define HROW     144              // LDS h row stride in shorts (288 B): <=2-way banks
#define GX_PER_T 131072           // gx elements per timestep (256 batch * 512 gates)

typedef __attribute__((ext_vector_type(8))) short short8;
typedef __attribute__((ext_vector_type(4))) short shortx4;
typedef __attribute__((ext_vector_type(4))) float f32x4;

__device__ __forceinline__ void barrier_nodrain() {
    // s_barrier WITHOUT the compiler's vmcnt(0) drain: LDS consistency only.
    // Outstanding global loads are wave-private (register dests) -> safe.
    __asm__ __volatile__("s_waitcnt lgkmcnt(0)\n\ts_barrier" ::: "memory");
}

__device__ __forceinline__ float sigmoidf_(float x) {
    return 1.0f / (1.0f + __expf(-x));
}
__device__ __forceinline__ float tanhf_(float x) {
    float e = __expf(2.0f * x);
    return 1.0f - 2.0f / (e + 1.0f);
}
__device__ __forceinline__ unsigned short f2bf(float x) {  // fp32 -> bf16 RNE
    union { float f; unsigned u; } v; v.f = x;
    unsigned r = v.u + 0x7fffu + ((v.u >> 16) & 1u);
    return (unsigned short)(r >> 16);
}
__device__ __forceinline__ float bf2f(short b) {
    union { unsigned u; float f; } v;
    v.u = ((unsigned)(unsigned short)b) << 16;
    return v.f;
}
__device__ __forceinline__ unsigned packbf(float lo, float hi) {
    return ((unsigned)f2bf(hi) << 16) | (unsigned)f2bf(lo);
}

// Permuted gx layout: idx(t,batch,gate) =
//   t*131072 + ((((batch>>2)*4 + gate>>7)*8 + (gate>>4)&7)*4 + (gate>>2)&3)*16
//            + (batch&3)*4 + (gate&3)
__device__ __forceinline__ size_t gx_idx(int t, int batch, int gate) {
    return (size_t)t * GX_PER_T +
           (size_t)(((((batch >> 2) * 4 + (gate >> 7)) * 8 + ((gate >> 4) & 7)) * 4 +
                     ((gate >> 2) & 3))) * 16 +
           (size_t)((batch & 3) * 4 + (gate & 3));
}

// ---------------------------------------------------------------------------
// bf16 MFMA GEMM: per chunk M = TC*256 (m=(tl,batch)), N = 512 gates, K = 256.
// Block 128x128 tile, 256 thr = 4 waves, each wave 64x64 (4x4 MFMA tiles).
// K staged in 8 slices of 32 (fp32 -> bf16 convert into LDS).
__global__ __launch_bounds__(256, 2) void gemm_gx_kernel(
    const float* __restrict__ x, const float* __restrict__ Wih,
    const float* __restrict__ bih, const float* __restrict__ bhh,
    unsigned short* __restrict__ gxb, int t0)
{
    __shared__ __align__(16) short As[128 * 32];
    __shared__ __align__(16) short Bs[128 * 32];
    const int tid = threadIdx.x;
    const int mt  = blockIdx.x;            // 0..2*TC-1
    const int nt  = blockIdx.y;            // 0..3 (== gate type g)
    const int tl  = mt >> 1;
    const int b0  = (mt & 1) * 128;
    const int n0  = nt * 128;

    const int w    = tid >> 6;
    const int lane = tid & 63;
    const int n    = lane & 15;
    const int quad = lane >> 4;
    const int mq   = w & 1;                // wave m-half
    const int nq   = w >> 1;               // wave n-half

    // staging role: thread covers row=tid>>1, k-halfslice=(tid&1)*16
    const int srow = tid >> 1;
    const int skh  = (tid & 1) * 16;
    const float* xrow = x + ((size_t)(b0 + srow) * TSEQ + (size_t)(t0 + tl)) * ISZ + skh;
    const float* wrow = Wih + (size_t)(n0 + srow) * ISZ + skh;

    f32x4 acc[4][4];
#pragma unroll
    for (int mi = 0; mi < 4; ++mi)
#pragma unroll
        for (int ni = 0; ni < 4; ++ni)
            acc[mi][ni] = (f32x4){0.f, 0.f, 0.f, 0.f};

    // prefetch slice 0
    float4 pa[4], pb[4];
#pragma unroll
    for (int j = 0; j < 4; ++j) {
        pa[j] = *(const float4*)(xrow + j * 4);
        pb[j] = *(const float4*)(wrow + j * 4);
    }

    for (int ks = 0; ks < 8; ++ks) {
        if (ks) barrier_nodrain();         // prev compute's LDS reads retired
        // convert + write LDS (2x b128 each for A and B)
        unsigned ua[8], ub[8];
#pragma unroll
        for (int j = 0; j < 4; ++j) {
            ua[2 * j]     = packbf(pa[j].x, pa[j].y);
            ua[2 * j + 1] = packbf(pa[j].z, pa[j].w);
            ub[2 * j]     = packbf(pb[j].x, pb[j].y);
            ub[2 * j + 1] = packbf(pb[j].z, pb[j].w);
        }
        *(uint4*)(&As[srow * 32 + skh])     = (uint4){ua[0], ua[1], ua[2], ua[3]};
        *(uint4*)(&As[srow * 32 + skh + 8]) = (uint4){ua[4], ua[5], ua[6], ua[7]};
        *(uint4*)(&Bs[srow * 32 + skh])     = (uint4){ub[0], ub[1], ub[2], ub[3]};
        *(uint4*)(&Bs[srow * 32 + skh + 8]) = (uint4){ub[4], ub[5], ub[6], ub[7]};

        // prefetch next slice (stays in flight across the raw barrier)
        if (ks < 7) {
#pragma unroll
            for (int j = 0; j < 4; ++j) {
                pa[j] = *(const float4*)(xrow + (ks + 1) * 32 + j * 4);
                pb[j] = *(const float4*)(wrow + (ks + 1) * 32 + j * 4);
            }
        }
        barrier_nodrain();

        short8 af[4], bf[4];
#pragma unroll
        for (int mi = 0; mi < 4; ++mi)
            af[mi] = *(const short8*)(&As[((mq * 4 + mi) * 16 + n) * 32 + quad * 8]);
#pragma unroll
        for (int ni = 0; ni < 4; ++ni)
            bf[ni] = *(const short8*)(&Bs[((nq * 4 + ni) * 16 + n) * 32 + quad * 8]);
#pragma unroll
        for (int mi = 0; mi < 4; ++mi)
#pragma unroll
            for (int ni = 0; ni < 4; ++ni)
                acc[mi][ni] = __builtin_amdgcn_mfma_f32_16x16x32_bf16(
                    af[mi], bf[ni], acc[mi][ni], 0, 0, 0);
    }

    // epilogue: bias + bf16 + permuted scatter store
#pragma unroll
    for (int ni = 0; ni < 4; ++ni) {
        const int gate = n0 + nq * 64 + ni * 16 + n;
        const float bias = bih[gate] + bhh[gate];
#pragma unroll
        for (int mi = 0; mi < 4; ++mi) {
            const int bb = b0 + mq * 64 + mi * 16 + quad * 4;   // batch base (mult of 4)
            const size_t base = gx_idx(tl, bb, gate);
#pragma unroll
            for (int r = 0; r < 4; ++r)                          // reg r == batch&3
                gxb[base + (size_t)r * 4] = f2bf(acc[mi][ni][r] + bias);
        }
    }
}

// ---------------------------------------------------------------------------
// MFMA recurrence. 64 blocks x 512 thr (8 waves), RB=4 batch rows per block.
// Wave w owns gate-tiles {w,8+w,16+w,24+w} (i/f/g/o for j in [16w,16w+16)).
// D cols 0..3 = real batches; cols 4..15 compute bounded garbage (never stored).
__global__ __launch_bounds__(512, 2) void lstm_mfma_kernel(
    const unsigned short* __restrict__ gxb, const float* __restrict__ Whh,
    float* __restrict__ hc, int first)
{
    __shared__ __align__(16) short h_lds[2 * RB * HROW];
    const int blk  = blockIdx.x;
    const int b0   = blk * RB;
    const int tid  = threadIdx.x;
    const int w    = tid >> 6;
    const int lane = tid & 63;
    const int n    = lane & 15;
    const int quad = lane >> 4;
    const int nb   = n & 3;

    // static A-frags: W_hh[128g + 16w + n][32ks + 8quad + i] as bf16
    short8 Af[4][4];
#pragma unroll
    for (int g = 0; g < 4; ++g) {
        const float* row = Whh + (size_t)(128 * g + 16 * w + n) * HSZ + 8 * quad;
#pragma unroll
        for (int ks = 0; ks < 4; ++ks)
#pragma unroll
            for (int i = 0; i < 8; ++i)
                Af[g][ks][i] = (short)f2bf(row[32 * ks + i]);
    }

    const int j0 = 16 * w + 4 * quad;
    float c4[4] = {0.f, 0.f, 0.f, 0.f};
    float hl[4] = {0.f, 0.f, 0.f, 0.f};
    shortx4 hinit = {0, 0, 0, 0};
    if (!first && n < RB) {
        const float4 hv = *(const float4*)(hc + (size_t)(b0 + n) * HSZ + j0);
        const float4 cv = *(const float4*)(hc + (size_t)BATCH * HSZ +
                                           (size_t)(b0 + n) * HSZ + j0);
        c4[0] = cv.x; c4[1] = cv.y; c4[2] = cv.z; c4[3] = cv.w;
        hinit = (shortx4){(short)f2bf(hv.x), (short)f2bf(hv.y),
                          (short)f2bf(hv.z), (short)f2bf(hv.w)};
    }
    if (n < RB) *(shortx4*)(&h_lds[n * HROW + j0]) = hinit;

    // gx base (per gate type g); lane-active only for n < 4
    const unsigned short* gp[4];
#pragma unroll
    for (int g = 0; g < 4; ++g)
        gp[g] = gxb + (size_t)((((blk * 4 + g) * 8 + w) * 4 + quad) * 16 + n * 4);

    shortx4 gq[2][4];
#pragma unroll
    for (int u = 0; u < 2; ++u)
#pragma unroll
        for (int g = 0; g < 4; ++g) gq[u][g] = (shortx4){0, 0, 0, 0};
    if (n < RB) {
#pragma unroll
        for (int g = 0; g < 4; ++g) {
            gq[0][g] = *(const shortx4*)(gp[g]);
            gq[1][g] = *(const shortx4*)(gp[g] + GX_PER_T);
        }
    }

    barrier_nodrain();

    for (int t = 0; t < TC; t += 2) {
#pragma unroll
        for (int u = 0; u < 2; ++u) {
            const int tt = t + u;                       // tt & 1 == u
            const short* hb_r = h_lds + u * (RB * HROW);
            short*       hb_w = h_lds + (u ^ 1) * (RB * HROW);

            short8 Bf[4];
#pragma unroll
            for (int ks = 0; ks < 4; ++ks)
                Bf[ks] = *(const short8*)(&hb_r[nb * HROW + 32 * ks + 8 * quad]);

            f32x4 acc[4];
#pragma unroll
            for (int g = 0; g < 4; ++g)
#pragma unroll
                for (int r = 0; r < 4; ++r) acc[g][r] = bf2f(gq[u][g][r]);

            if (n < RB && tt + 2 < TC) {                // depth-2 prefetch
#pragma unroll
                for (int g = 0; g < 4; ++g)
                    gq[u][g] = *(const shortx4*)(gp[g] + (size_t)(tt + 2) * GX_PER_T);
            }

#pragma unroll
            for (int ks = 0; ks < 4; ++ks)
#pragma unroll
                for (int g = 0; g < 4; ++g)
                    acc[g] = __builtin_amdgcn_mfma_f32_16x16x32_bf16(
                        Af[g][ks], Bf[ks], acc[g], 0, 0, 0);

#pragma unroll
            for (int r = 0; r < 4; ++r) {
                const float ig = sigmoidf_(acc[0][r]);
                const float fg = sigmoidf_(acc[1][r]);
                const float gg = tanhf_(acc[2][r]);
                const float og = sigmoidf_(acc[3][r]);
                c4[r] = fg * c4[r] + ig * gg;
                hl[r] = og * tanhf_(c4[r]);
            }
            if (n < RB) {
                shortx4 hp = {(short)f2bf(hl[0]), (short)f2bf(hl[1]),
                              (short)f2bf(hl[2]), (short)f2bf(hl[3])};
                *(shortx4*)(&hb_w[n * HROW + j0]) = hp;
            }
            barrier_nodrain();
        }
    }

    if (n < RB) {
        *(float4*)(hc + (size_t)(b0 + n) * HSZ + j0) =
            (float4){hl[0], hl[1], hl[2], hl[3]};
        *(float4*)(hc + (size_t)BATCH * HSZ + (size_t)(b0 + n) * HSZ + j0) =
            (float4){c4[0], c4[1], c4[2], c4[3]};
    }
}

// ---------------------------------------------------------------------------
// MLP head: one block (64 threads) per batch row.
__global__ __launch_bounds__(64) void head_kernel(
    const float* __restrict__ hc,
    const float* __restrict__ W1, const float* __restrict__ b1,
    const float* __restrict__ W2, const float* __restrict__ b2,
    const float* __restrict__ W3, const float* __restrict__ b3,
    float* __restrict__ out)
{
    __shared__ float hs[HSZ];
    __shared__ float o1[64];
    __shared__ float o2[32];
    const int bidx = blockIdx.x;
    const int t = threadIdx.x;
    hs[t]      = hc[bidx * HSZ + t];
    hs[t + 64] = hc[bidx * HSZ + t + 64];
    __syncthreads();
    {
        float a = b1[t];
#pragma unroll 8
        for (int k = 0; k < HSZ; ++k) a += W1[t * HSZ + k] * hs[k];
        o1[t] = fmaxf(a, 0.0f);
    }
    __syncthreads();
    if (t < 32) {
        float a = b2[t];
#pragma unroll 8
        for (int k = 0; k < 64; ++k) a += W2[t * 64 + k] * o1[k];
        o2[t] = fmaxf(a, 0.0f);
    }
    __syncthreads();
    if (t < 4) {
        float a = b3[t];
#pragma unroll
        for (int k = 0; k < 32; ++k) a += W3[t * 32 + k] * o2[k];
        out[bidx * 4 + t] = a;
    }
}

// ---------------------------------------------------------------------------
extern "C" void kernel_launch(void* const* d_in, const int* in_sizes, int n_in,
                              void* d_out, int out_size, void* d_ws, size_t ws_size,
                              hipStream_t stream) {
    const float* x   = (const float*)d_in[0];
    const float* Wih = (const float*)d_in[1];
    const float* Whh = (const float*)d_in[2];
    const float* bih = (const float*)d_in[3];
    const float* bhh = (const float*)d_in[4];
    const float* W1  = (const float*)d_in[5];
    const float* b1  = (const float*)d_in[6];
    const float* W2  = (const float*)d_in[7];
    const float* b2  = (const float*)d_in[8];
    const float* W3  = (const float*)d_in[9];
    const float* b3  = (const float*)d_in[10];
    float* out = (float*)d_out;

    unsigned short* gxb = (unsigned short*)d_ws;                 // 33.55 MB bf16
    float* hc = (float*)((char*)d_ws + (size_t)TC * GX_PER_T * 2); // 256 KB h+c

    for (int c = 0; c < NCHUNK; ++c) {
        gemm_gx_kernel<<<dim3(2 * TC, 4), 256, 0, stream>>>(x, Wih, bih, bhh, gxb, c * TC);
        lstm_mfma_kernel<<<dim3(NBLK), 512, 0, stream>>>(gxb, Whh, hc, c == 0);
    }
    head_kernel<<<dim3(BATCH), 64, 0, stream>>>(hc, W1, b1, W2, b2, W3, b3, out);
}

// Round 5
// 1119.888 us; speedup vs baseline: 1.3212x; 1.0280x over previous
//
#include <hip/hip_runtime.h>

// LSTM: B=256, T=512, I=256, H=128 (4H=512 gates), then MLP 128->64->32->4.
//   gemm_gx_kernel : bf16 MFMA GEMM, gx = x @ W_ih^T + bias, bf16 PERMUTED
//                    fragment layout (direct acc-init for the recurrence).
//   lstm_mfma_kernel : 64 blocks (RB=4 batch rows) x 512 thr (8 waves).
//       Per step: gates[512x16] = W_hh @ h^T via mfma_16x16x32_bf16. W_hh static
//       in VGPRs. h double-buffered in LDS, raw lgkmcnt-only barrier.
//       ROUND 5: depth-4 branch-free register prefetch of gx (clamped lane addr)
//       so gx miss latency (~600-2000 cyc) is covered by ~3.5 steps of slack.
//   head_kernel : tiny MLP per row.

#define TC       128
#define NCHUNK   4
#define BATCH    256
#define TSEQ     512
#define ISZ      256
#define HSZ      128
#define G4       512
#define RB       4
#define NBLK     (BATCH / RB)
#define HROW     136              // LDS h row stride in shorts (272 B)
#define GX_PER_T 131072           // gx elements per timestep
#define PF       4                // gx prefetch depth in steps (TC % PF == 0, even)

typedef __attribute__((ext_vector_type(8))) short short8;
typedef __attribute__((ext_vector_type(4))) short shortx4;
typedef __attribute__((ext_vector_type(4))) float f32x4;

__device__ __forceinline__ void barrier_nodrain() {
    // s_barrier WITHOUT the compiler's vmcnt(0) drain: LDS consistency only.
    // Outstanding global loads are wave-private (register dests) -> safe.
    __asm__ __volatile__("s_waitcnt lgkmcnt(0)\n\ts_barrier" ::: "memory");
}

__device__ __forceinline__ float sigmoidf_(float x) {
    return 1.0f / (1.0f + __expf(-x));
}
__device__ __forceinline__ float tanhf_(float x) {
    float e = __expf(2.0f * x);
    return 1.0f - 2.0f / (e + 1.0f);
}
__device__ __forceinline__ unsigned short f2bf(float x) {  // fp32 -> bf16 RNE
    union { float f; unsigned u; } v; v.f = x;
    unsigned r = v.u + 0x7fffu + ((v.u >> 16) & 1u);
    return (unsigned short)(r >> 16);
}
__device__ __forceinline__ float bf2f(short b) {
    union { unsigned u; float f; } v;
    v.u = ((unsigned)(unsigned short)b) << 16;
    return v.f;
}
__device__ __forceinline__ unsigned packbf(float lo, float hi) {
    return ((unsigned)f2bf(hi) << 16) | (unsigned)f2bf(lo);
}

// Permuted gx layout (see gemm epilogue / recurrence gp[] — must stay in sync)
__device__ __forceinline__ size_t gx_idx(int t, int batch, int gate) {
    return (size_t)t * GX_PER_T +
           (size_t)(((((batch >> 2) * 4 + (gate >> 7)) * 8 + ((gate >> 4) & 7)) * 4 +
                     ((gate >> 2) & 3))) * 16 +
           (size_t)((batch & 3) * 4 + (gate & 3));
}

// ---------------------------------------------------------------------------
// bf16 MFMA GEMM: per chunk M = TC*256 (m=(tl,batch)), N = 512 gates, K = 256.
__global__ __launch_bounds__(256, 2) void gemm_gx_kernel(
    const float* __restrict__ x, const float* __restrict__ Wih,
    const float* __restrict__ bih, const float* __restrict__ bhh,
    unsigned short* __restrict__ gxb, int t0)
{
    __shared__ __align__(16) short As[128 * 32];
    __shared__ __align__(16) short Bs[128 * 32];
    const int tid = threadIdx.x;
    const int mt  = blockIdx.x;
    const int nt  = blockIdx.y;
    const int tl  = mt >> 1;
    const int b0  = (mt & 1) * 128;
    const int n0  = nt * 128;

    const int w    = tid >> 6;
    const int lane = tid & 63;
    const int n    = lane & 15;
    const int quad = lane >> 4;
    const int mq   = w & 1;
    const int nq   = w >> 1;

    const int srow = tid >> 1;
    const int skh  = (tid & 1) * 16;
    const float* xrow = x + ((size_t)(b0 + srow) * TSEQ + (size_t)(t0 + tl)) * ISZ + skh;
    const float* wrow = Wih + (size_t)(n0 + srow) * ISZ + skh;

    f32x4 acc[4][4];
#pragma unroll
    for (int mi = 0; mi < 4; ++mi)
#pragma unroll
        for (int ni = 0; ni < 4; ++ni)
            acc[mi][ni] = (f32x4){0.f, 0.f, 0.f, 0.f};

    float4 pa[4], pb[4];
#pragma unroll
    for (int j = 0; j < 4; ++j) {
        pa[j] = *(const float4*)(xrow + j * 4);
        pb[j] = *(const float4*)(wrow + j * 4);
    }

    for (int ks = 0; ks < 8; ++ks) {
        if (ks) barrier_nodrain();
        unsigned ua[8], ub[8];
#pragma unroll
        for (int j = 0; j < 4; ++j) {
            ua[2 * j]     = packbf(pa[j].x, pa[j].y);
            ua[2 * j + 1] = packbf(pa[j].z, pa[j].w);
            ub[2 * j]     = packbf(pb[j].x, pb[j].y);
            ub[2 * j + 1] = packbf(pb[j].z, pb[j].w);
        }
        *(uint4*)(&As[srow * 32 + skh])     = (uint4){ua[0], ua[1], ua[2], ua[3]};
        *(uint4*)(&As[srow * 32 + skh + 8]) = (uint4){ua[4], ua[5], ua[6], ua[7]};
        *(uint4*)(&Bs[srow * 32 + skh])     = (uint4){ub[0], ub[1], ub[2], ub[3]};
        *(uint4*)(&Bs[srow * 32 + skh + 8]) = (uint4){ub[4], ub[5], ub[6], ub[7]};

        if (ks < 7) {
#pragma unroll
            for (int j = 0; j < 4; ++j) {
                pa[j] = *(const float4*)(xrow + (ks + 1) * 32 + j * 4);
                pb[j] = *(const float4*)(wrow + (ks + 1) * 32 + j * 4);
            }
        }
        barrier_nodrain();

        short8 af[4], bf[4];
#pragma unroll
        for (int mi = 0; mi < 4; ++mi)
            af[mi] = *(const short8*)(&As[((mq * 4 + mi) * 16 + n) * 32 + quad * 8]);
#pragma unroll
        for (int ni = 0; ni < 4; ++ni)
            bf[ni] = *(const short8*)(&Bs[((nq * 4 + ni) * 16 + n) * 32 + quad * 8]);
#pragma unroll
        for (int mi = 0; mi < 4; ++mi)
#pragma unroll
            for (int ni = 0; ni < 4; ++ni)
                acc[mi][ni] = __builtin_amdgcn_mfma_f32_16x16x32_bf16(
                    af[mi], bf[ni], acc[mi][ni], 0, 0, 0);
    }

#pragma unroll
    for (int ni = 0; ni < 4; ++ni) {
        const int gate = n0 + nq * 64 + ni * 16 + n;
        const float bias = bih[gate] + bhh[gate];
#pragma unroll
        for (int mi = 0; mi < 4; ++mi) {
            const int bb = b0 + mq * 64 + mi * 16 + quad * 4;
            const size_t base = gx_idx(tl, bb, gate);
#pragma unroll
            for (int r = 0; r < 4; ++r)
                gxb[base + (size_t)r * 4] = f2bf(acc[mi][ni][r] + bias);
        }
    }
}

// ---------------------------------------------------------------------------
// MFMA recurrence. 64 blocks x 512 thr (8 waves), RB=4 batch rows per block.
// Wave w owns gate-tiles {w,8+w,16+w,24+w} (i/f/g/o for j in [16w,16w+16)).
// D cols 0..3 real; cols 4..15 duplicate gx of col n&3 with garbage h (unused).
__global__ __launch_bounds__(512, 2) void lstm_mfma_kernel(
    const unsigned short* __restrict__ gxb, const float* __restrict__ Whh,
    float* __restrict__ hc, int first)
{
    __shared__ __align__(16) short h_lds[2 * RB * HROW];
    const int blk  = blockIdx.x;
    const int b0   = blk * RB;
    const int tid  = threadIdx.x;
    const int w    = tid >> 6;
    const int lane = tid & 63;
    const int n    = lane & 15;
    const int quad = lane >> 4;
    const int nb   = n & 3;              // clamped batch col (real for n<4)

    // static A-frags: W_hh[128g + 16w + n][32ks + 8quad + i] as bf16
    short8 Af[4][4];
#pragma unroll
    for (int g = 0; g < 4; ++g) {
        const float* row = Whh + (size_t)(128 * g + 16 * w + n) * HSZ + 8 * quad;
#pragma unroll
        for (int ks = 0; ks < 4; ++ks)
#pragma unroll
            for (int i = 0; i < 8; ++i)
                Af[g][ks][i] = (short)f2bf(row[32 * ks + i]);
    }

    const int j0 = 16 * w + 4 * quad;
    float c4[4] = {0.f, 0.f, 0.f, 0.f};
    float hl[4] = {0.f, 0.f, 0.f, 0.f};
    // branch-free init: all lanes load via clamped nb (n<4 lanes get real values)
    if (!first) {
        const float4 cv = *(const float4*)(hc + (size_t)BATCH * HSZ +
                                           (size_t)(b0 + nb) * HSZ + j0);
        c4[0] = cv.x; c4[1] = cv.y; c4[2] = cv.z; c4[3] = cv.w;
        const float4 hv = *(const float4*)(hc + (size_t)(b0 + nb) * HSZ + j0);
        if (n < RB) {
            shortx4 hp = {(short)f2bf(hv.x), (short)f2bf(hv.y),
                          (short)f2bf(hv.z), (short)f2bf(hv.w)};
            *(shortx4*)(&h_lds[n * HROW + j0]) = hp;
        }
    } else if (n < RB) {
        *(shortx4*)(&h_lds[n * HROW + j0]) = (shortx4){0, 0, 0, 0};
    }

    // gx base per gate type g, branch-free (clamped nb): 8-B dwordx2 loads
    const unsigned short* gp[4];
#pragma unroll
    for (int g = 0; g < 4; ++g)
        gp[g] = gxb + (size_t)((((blk * 4 + g) * 8 + w) * 4 + quad) * 16 + nb * 4);

    // depth-PF prefetch ring: gq[d] holds gx for step (t_base + d)
    shortx4 gq[PF][4];
#pragma unroll
    for (int d = 0; d < PF; ++d)
#pragma unroll
        for (int g = 0; g < 4; ++g)
            gq[d][g] = *(const shortx4*)(gp[g] + (size_t)d * GX_PER_T);

    barrier_nodrain();

    for (int t = 0; t < TC; t += PF) {
#pragma unroll
        for (int u = 0; u < PF; ++u) {
            const int tt = t + u;                        // tt & 1 == u & 1
            const short* hb_r = h_lds + (u & 1) * (RB * HROW);
            short*       hb_w = h_lds + ((u & 1) ^ 1) * (RB * HROW);

            short8 Bf[4];
#pragma unroll
            for (int ks = 0; ks < 4; ++ks)
                Bf[ks] = *(const short8*)(&hb_r[nb * HROW + 32 * ks + 8 * quad]);

            f32x4 acc[4];
#pragma unroll
            for (int g = 0; g < 4; ++g)
#pragma unroll
                for (int r = 0; r < 4; ++r) acc[g][r] = bf2f(gq[u][g][r]);

            // refill slot u for step tt+PF (clamped at chunk end; value unused then)
            {
                const int tf = (tt + PF < TC) ? (tt + PF) : (TC - 1);
#pragma unroll
                for (int g = 0; g < 4; ++g)
                    gq[u][g] = *(const shortx4*)(gp[g] + (size_t)tf * GX_PER_T);
            }

#pragma unroll
            for (int ks = 0; ks < 4; ++ks)
#pragma unroll
                for (int g = 0; g < 4; ++g)
                    acc[g] = __builtin_amdgcn_mfma_f32_16x16x32_bf16(
                        Af[g][ks], Bf[ks], acc[g], 0, 0, 0);

#pragma unroll
            for (int r = 0; r < 4; ++r) {
                const float ig = sigmoidf_(acc[0][r]);
                const float fg = sigmoidf_(acc[1][r]);
                const float gg = tanhf_(acc[2][r]);
                const float og = sigmoidf_(acc[3][r]);
                c4[r] = fg * c4[r] + ig * gg;
                hl[r] = og * tanhf_(c4[r]);
            }
            if (n < RB) {
                shortx4 hp = {(short)f2bf(hl[0]), (short)f2bf(hl[1]),
                              (short)f2bf(hl[2]), (short)f2bf(hl[3])};
                *(shortx4*)(&hb_w[n * HROW + j0]) = hp;
            }
            barrier_nodrain();
        }
    }

    if (n < RB) {
        *(float4*)(hc + (size_t)(b0 + n) * HSZ + j0) =
            (float4){hl[0], hl[1], hl[2], hl[3]};
        *(float4*)(hc + (size_t)BATCH * HSZ + (size_t)(b0 + n) * HSZ + j0) =
            (float4){c4[0], c4[1], c4[2], c4[3]};
    }
}

// ---------------------------------------------------------------------------
// MLP head: one block (64 threads) per batch row.
__global__ __launch_bounds__(64) void head_kernel(
    const float* __restrict__ hc,
    const float* __restrict__ W1, const float* __restrict__ b1,
    const float* __restrict__ W2, const float* __restrict__ b2,
    const float* __restrict__ W3, const float* __restrict__ b3,
    float* __restrict__ out)
{
    __shared__ float hs[HSZ];
    __shared__ float o1[64];
    __shared__ float o2[32];
    const int bidx = blockIdx.x;
    const int t = threadIdx.x;
    hs[t]      = hc[bidx * HSZ + t];
    hs[t + 64] = hc[bidx * HSZ + t + 64];
    __syncthreads();
    {
        float a = b1[t];
#pragma unroll 8
        for (int k = 0; k < HSZ; ++k) a += W1[t * HSZ + k] * hs[k];
        o1[t] = fmaxf(a, 0.0f);
    }
    __syncthreads();
    if (t < 32) {
        float a = b2[t];
#pragma unroll 8
        for (int k = 0; k < 64; ++k) a += W2[t * 64 + k] * o1[k];
        o2[t] = fmaxf(a, 0.0f);
    }
    __syncthreads();
    if (t < 4) {
        float a = b3[t];
#pragma unroll
        for (int k = 0; k < 32; ++k) a += W3[t * 32 + k] * o2[k];
        out[bidx * 4 + t] = a;
    }
}

// ---------------------------------------------------------------------------
extern "C" void kernel_launch(void* const* d_in, const int* in_sizes, int n_in,
                              void* d_out, int out_size, void* d_ws, size_t ws_size,
                              hipStream_t stream) {
    const float* x   = (const float*)d_in[0];
    const float* Wih = (const float*)d_in[1];
    const float* Whh = (const float*)d_in[2];
    const float* bih = (const float*)d_in[3];
    const float* bhh = (const float*)d_in[4];
    const float* W1  = (const float*)d_in[5];
    const float* b1  = (const float*)d_in[6];
    const float* W2  = (const float*)d_in[7];
    const float* b2  = (const float*)d_in[8];
    const float* W3  = (const float*)d_in[9];
    const float* b3  = (const float*)d_in[10];
    float* out = (float*)d_out;

    unsigned short* gxb = (unsigned short*)d_ws;                   // 33.55 MB bf16
    float* hc = (float*)((char*)d_ws + (size_t)TC * GX_PER_T * 2); // 256 KB h+c

    for (int c = 0; c < NCHUNK; ++c) {
        gemm_gx_kernel<<<dim3(2 * TC, 4), 256, 0, stream>>>(x, Wih, bih, bhh, gxb, c * TC);
        lstm_mfma_kernel<<<dim3(NBLK), 512, 0, stream>>>(gxb, Whh, hc, c == 0);
    }
    head_kernel<<<dim3(BATCH), 64, 0, stream>>>(hc, W1, b1, W2, b2, W3, b3, out);
}

// Round 6
// 780.635 us; speedup vs baseline: 1.8954x; 1.4346x over previous
//
#include <hip/hip_runtime.h>

// LSTM: B=256, T=512, I=256, H=128 (4H=512 gates), then MLP 128->64->32->4.
//   gemm_gx_kernel : bf16 MFMA GEMM, gx = x @ W_ih^T + bias, bf16 PERMUTED
//                    fragment layout. ROUND 6: double-buffered LDS, 1 barrier/slice.
//   lstm_mfma_kernel : 64 blocks (RB=4) x 512 thr (8 waves). W_hh static in VGPRs,
//       h double-buffered in LDS, raw lgkmcnt-only barriers, depth-4 gx prefetch.
//       ROUND 6: activations use v_rcp_f32 instead of precise fp32 division
//       (was ~10 VALU ops per division x 20 divisions/thread/step -> VALU-bound).
//   head_kernel : tiny MLP per row.

#define TC       128
#define NCHUNK   4
#define BATCH    256
#define TSEQ     512
#define ISZ      256
#define HSZ      128
#define G4       512
#define RB       4
#define NBLK     (BATCH / RB)
#define HROW     136              // LDS h row stride in shorts (272 B)
#define GX_PER_T 131072           // gx elements per timestep
#define PF       4                // gx prefetch depth in steps

typedef __attribute__((ext_vector_type(8))) short short8;
typedef __attribute__((ext_vector_type(4))) short shortx4;
typedef __attribute__((ext_vector_type(4))) float f32x4;

__device__ __forceinline__ void barrier_nodrain() {
    // s_barrier WITHOUT the compiler's vmcnt(0) drain: LDS consistency only.
    __asm__ __volatile__("s_waitcnt lgkmcnt(0)\n\ts_barrier" ::: "memory");
}

__device__ __forceinline__ float fast_rcp(float x) {
    return __builtin_amdgcn_rcpf(x);          // v_rcp_f32, ~1 ulp
}
__device__ __forceinline__ float sigmoidf_(float x) {
    return fast_rcp(1.0f + __expf(-x));       // mul+exp+add+rcp
}
__device__ __forceinline__ float tanhf_(float x) {
    float e = __expf(2.0f * x);               // inf-safe: rcp(inf)=0 -> 1; e->0 -> -1
    return 1.0f - 2.0f * fast_rcp(e + 1.0f);
}
__device__ __forceinline__ unsigned short f2bf(float x) {  // fp32 -> bf16 RNE
    union { float f; unsigned u; } v; v.f = x;
    unsigned r = v.u + 0x7fffu + ((v.u >> 16) & 1u);
    return (unsigned short)(r >> 16);
}
__device__ __forceinline__ float bf2f(short b) {
    union { unsigned u; float f; } v;
    v.u = ((unsigned)(unsigned short)b) << 16;
    return v.f;
}
__device__ __forceinline__ unsigned packbf(float lo, float hi) {
    return ((unsigned)f2bf(hi) << 16) | (unsigned)f2bf(lo);
}

// Permuted gx layout (gemm epilogue / recurrence gp[] must stay in sync)
__device__ __forceinline__ size_t gx_idx(int t, int batch, int gate) {
    return (size_t)t * GX_PER_T +
           (size_t)(((((batch >> 2) * 4 + (gate >> 7)) * 8 + ((gate >> 4) & 7)) * 4 +
                     ((gate >> 2) & 3))) * 16 +
           (size_t)((batch & 3) * 4 + (gate & 3));
}

// ---------------------------------------------------------------------------
// bf16 MFMA GEMM: per chunk M = TC*256 (m=(tl,batch)), N = 512 gates, K = 256.
// Double-buffered LDS: stage slice ks+1 while computing slice ks; 1 barrier/slice.
__global__ __launch_bounds__(256, 2) void gemm_gx_kernel(
    const float* __restrict__ x, const float* __restrict__ Wih,
    const float* __restrict__ bih, const float* __restrict__ bhh,
    unsigned short* __restrict__ gxb, int t0)
{
    __shared__ __align__(16) short As[2][128 * 32];
    __shared__ __align__(16) short Bs[2][128 * 32];
    const int tid = threadIdx.x;
    const int mt  = blockIdx.x;
    const int nt  = blockIdx.y;
    const int tl  = mt >> 1;
    const int b0  = (mt & 1) * 128;
    const int n0  = nt * 128;

    const int w    = tid >> 6;
    const int lane = tid & 63;
    const int n    = lane & 15;
    const int quad = lane >> 4;
    const int mq   = w & 1;
    const int nq   = w >> 1;

    const int srow = tid >> 1;
    const int skh  = (tid & 1) * 16;
    const float* xrow = x + ((size_t)(b0 + srow) * TSEQ + (size_t)(t0 + tl)) * ISZ + skh;
    const float* wrow = Wih + (size_t)(n0 + srow) * ISZ + skh;

    f32x4 acc[4][4];
#pragma unroll
    for (int mi = 0; mi < 4; ++mi)
#pragma unroll
        for (int ni = 0; ni < 4; ++ni)
            acc[mi][ni] = (f32x4){0.f, 0.f, 0.f, 0.f};

    // stage slice 0 into buffer 0
    {
        float4 pa[4], pb[4];
#pragma unroll
        for (int j = 0; j < 4; ++j) {
            pa[j] = *(const float4*)(xrow + j * 4);
            pb[j] = *(const float4*)(wrow + j * 4);
        }
        unsigned ua[8], ub[8];
#pragma unroll
        for (int j = 0; j < 4; ++j) {
            ua[2 * j]     = packbf(pa[j].x, pa[j].y);
            ua[2 * j + 1] = packbf(pa[j].z, pa[j].w);
            ub[2 * j]     = packbf(pb[j].x, pb[j].y);
            ub[2 * j + 1] = packbf(pb[j].z, pb[j].w);
        }
        *(uint4*)(&As[0][srow * 32 + skh])     = (uint4){ua[0], ua[1], ua[2], ua[3]};
        *(uint4*)(&As[0][srow * 32 + skh + 8]) = (uint4){ua[4], ua[5], ua[6], ua[7]};
        *(uint4*)(&Bs[0][srow * 32 + skh])     = (uint4){ub[0], ub[1], ub[2], ub[3]};
        *(uint4*)(&Bs[0][srow * 32 + skh + 8]) = (uint4){ub[4], ub[5], ub[6], ub[7]};
    }
    barrier_nodrain();

    for (int ks = 0; ks < 8; ++ks) {
        const int cur = ks & 1;
        const int nxt = cur ^ 1;

        // issue next slice's global loads first (latency hidden under MFMAs)
        float4 pa[4], pb[4];
        if (ks < 7) {
#pragma unroll
            for (int j = 0; j < 4; ++j) {
                pa[j] = *(const float4*)(xrow + (ks + 1) * 32 + j * 4);
                pb[j] = *(const float4*)(wrow + (ks + 1) * 32 + j * 4);
            }
        }

        short8 af[4], bf[4];
#pragma unroll
        for (int mi = 0; mi < 4; ++mi)
            af[mi] = *(const short8*)(&As[cur][((mq * 4 + mi) * 16 + n) * 32 + quad * 8]);
#pragma unroll
        for (int ni = 0; ni < 4; ++ni)
            bf[ni] = *(const short8*)(&Bs[cur][((nq * 4 + ni) * 16 + n) * 32 + quad * 8]);
#pragma unroll
        for (int mi = 0; mi < 4; ++mi)
#pragma unroll
            for (int ni = 0; ni < 4; ++ni)
                acc[mi][ni] = __builtin_amdgcn_mfma_f32_16x16x32_bf16(
                    af[mi], bf[ni], acc[mi][ni], 0, 0, 0);

        // convert + store next slice into the other buffer
        if (ks < 7) {
            unsigned ua[8], ub[8];
#pragma unroll
            for (int j = 0; j < 4; ++j) {
                ua[2 * j]     = packbf(pa[j].x, pa[j].y);
                ua[2 * j + 1] = packbf(pa[j].z, pa[j].w);
                ub[2 * j]     = packbf(pb[j].x, pb[j].y);
                ub[2 * j + 1] = packbf(pb[j].z, pb[j].w);
            }
            *(uint4*)(&As[nxt][srow * 32 + skh])     = (uint4){ua[0], ua[1], ua[2], ua[3]};
            *(uint4*)(&As[nxt][srow * 32 + skh + 8]) = (uint4){ua[4], ua[5], ua[6], ua[7]};
            *(uint4*)(&Bs[nxt][srow * 32 + skh])     = (uint4){ub[0], ub[1], ub[2], ub[3]};
            *(uint4*)(&Bs[nxt][srow * 32 + skh + 8]) = (uint4){ub[4], ub[5], ub[6], ub[7]};
        }
        barrier_nodrain();   // writes to nxt done; reads of cur drained (lgkmcnt)
    }

#pragma unroll
    for (int ni = 0; ni < 4; ++ni) {
        const int gate = n0 + nq * 64 + ni * 16 + n;
        const float bias = bih[gate] + bhh[gate];
#pragma unroll
        for (int mi = 0; mi < 4; ++mi) {
            const int bb = b0 + mq * 64 + mi * 16 + quad * 4;
            const size_t base = gx_idx(tl, bb, gate);
#pragma unroll
            for (int r = 0; r < 4; ++r)
                gxb[base + (size_t)r * 4] = f2bf(acc[mi][ni][r] + bias);
        }
    }
}

// ---------------------------------------------------------------------------
// MFMA recurrence. 64 blocks x 512 thr (8 waves), RB=4 batch rows per block.
__global__ __launch_bounds__(512, 2) void lstm_mfma_kernel(
    const unsigned short* __restrict__ gxb, const float* __restrict__ Whh,
    float* __restrict__ hc, int first)
{
    __shared__ __align__(16) short h_lds[2 * RB * HROW];
    const int blk  = blockIdx.x;
    const int b0   = blk * RB;
    const int tid  = threadIdx.x;
    const int w    = tid >> 6;
    const int lane = tid & 63;
    const int n    = lane & 15;
    const int quad = lane >> 4;
    const int nb   = n & 3;

    // static A-frags: W_hh[128g + 16w + n][32ks + 8quad + i] as bf16
    short8 Af[4][4];
#pragma unroll
    for (int g = 0; g < 4; ++g) {
        const float* row = Whh + (size_t)(128 * g + 16 * w + n) * HSZ + 8 * quad;
#pragma unroll
        for (int ks = 0; ks < 4; ++ks)
#pragma unroll
            for (int i = 0; i < 8; ++i)
                Af[g][ks][i] = (short)f2bf(row[32 * ks + i]);
    }

    const int j0 = 16 * w + 4 * quad;
    float c4[4] = {0.f, 0.f, 0.f, 0.f};
    float hl[4] = {0.f, 0.f, 0.f, 0.f};
    if (!first) {
        const float4 cv = *(const float4*)(hc + (size_t)BATCH * HSZ +
                                           (size_t)(b0 + nb) * HSZ + j0);
        c4[0] = cv.x; c4[1] = cv.y; c4[2] = cv.z; c4[3] = cv.w;
        const float4 hv = *(const float4*)(hc + (size_t)(b0 + nb) * HSZ + j0);
        if (n < RB) {
            shortx4 hp = {(short)f2bf(hv.x), (short)f2bf(hv.y),
                          (short)f2bf(hv.z), (short)f2bf(hv.w)};
            *(shortx4*)(&h_lds[n * HROW + j0]) = hp;
        }
    } else if (n < RB) {
        *(shortx4*)(&h_lds[n * HROW + j0]) = (shortx4){0, 0, 0, 0};
    }

    const unsigned short* gp[4];
#pragma unroll
    for (int g = 0; g < 4; ++g)
        gp[g] = gxb + (size_t)((((blk * 4 + g) * 8 + w) * 4 + quad) * 16 + nb * 4);

    shortx4 gq[PF][4];
#pragma unroll
    for (int d = 0; d < PF; ++d)
#pragma unroll
        for (int g = 0; g < 4; ++g)
            gq[d][g] = *(const shortx4*)(gp[g] + (size_t)d * GX_PER_T);

    barrier_nodrain();

    for (int t = 0; t < TC; t += PF) {
#pragma unroll
        for (int u = 0; u < PF; ++u) {
            const int tt = t + u;
            const short* hb_r = h_lds + (u & 1) * (RB * HROW);
            short*       hb_w = h_lds + ((u & 1) ^ 1) * (RB * HROW);

            short8 Bf[4];
#pragma unroll
            for (int ks = 0; ks < 4; ++ks)
                Bf[ks] = *(const short8*)(&hb_r[nb * HROW + 32 * ks + 8 * quad]);

            f32x4 acc[4];
#pragma unroll
            for (int g = 0; g < 4; ++g)
#pragma unroll
                for (int r = 0; r < 4; ++r) acc[g][r] = bf2f(gq[u][g][r]);

            {
                const int tf = (tt + PF < TC) ? (tt + PF) : (TC - 1);
#pragma unroll
                for (int g = 0; g < 4; ++g)
                    gq[u][g] = *(const shortx4*)(gp[g] + (size_t)tf * GX_PER_T);
            }

#pragma unroll
            for (int ks = 0; ks < 4; ++ks)
#pragma unroll
                for (int g = 0; g < 4; ++g)
                    acc[g] = __builtin_amdgcn_mfma_f32_16x16x32_bf16(
                        Af[g][ks], Bf[ks], acc[g], 0, 0, 0);

#pragma unroll
            for (int r = 0; r < 4; ++r) {
                const float ig = sigmoidf_(acc[0][r]);
                const float fg = sigmoidf_(acc[1][r]);
                const float gg = tanhf_(acc[2][r]);
                const float og = sigmoidf_(acc[3][r]);
                c4[r] = fg * c4[r] + ig * gg;
                hl[r] = og * tanhf_(c4[r]);
            }
            if (n < RB) {
                shortx4 hp = {(short)f2bf(hl[0]), (short)f2bf(hl[1]),
                              (short)f2bf(hl[2]), (short)f2bf(hl[3])};
                *(shortx4*)(&hb_w[n * HROW + j0]) = hp;
            }
            barrier_nodrain();
        }
    }

    if (n < RB) {
        *(float4*)(hc + (size_t)(b0 + n) * HSZ + j0) =
            (float4){hl[0], hl[1], hl[2], hl[3]};
        *(float4*)(hc + (size_t)BATCH * HSZ + (size_t)(b0 + n) * HSZ + j0) =
            (float4){c4[0], c4[1], c4[2], c4[3]};
    }
}

// ---------------------------------------------------------------------------
// MLP head: one block (64 threads) per batch row.
__global__ __launch_bounds__(64) void head_kernel(
    const float* __restrict__ hc,
    const float* __restrict__ W1, const float* __restrict__ b1,
    const float* __restrict__ W2, const float* __restrict__ b2,
    const float* __restrict__ W3, const float* __restrict__ b3,
    float* __restrict__ out)
{
    __shared__ float hs[HSZ];
    __shared__ float o1[64];
    __shared__ float o2[32];
    const int bidx = blockIdx.x;
    const int t = threadIdx.x;
    hs[t]      = hc[bidx * HSZ + t];
    hs[t + 64] = hc[bidx * HSZ + t + 64];
    __syncthreads();
    {
        float a = b1[t];
#pragma unroll 8
        for (int k = 0; k < HSZ; ++k) a += W1[t * HSZ + k] * hs[k];
        o1[t] = fmaxf(a, 0.0f);
    }
    __syncthreads();
    if (t < 32) {
        float a = b2[t];
#pragma unroll 8
        for (int k = 0; k < 64; ++k) a += W2[t * 64 + k] * o1[k];
        o2[t] = fmaxf(a, 0.0f);
    }
    __syncthreads();
    if (t < 4) {
        float a = b3[t];
#pragma unroll
        for (int k = 0; k < 32; ++k) a += W3[t * 32 + k] * o2[k];
        out[bidx * 4 + t] = a;
    }
}

// ---------------------------------------------------------------------------
extern "C" void kernel_launch(void* const* d_in, const int* in_sizes, int n_in,
                              void* d_out, int out_size, void* d_ws, size_t ws_size,
                              hipStream_t stream) {
    const float* x   = (const float*)d_in[0];
    const float* Wih = (const float*)d_in[1];
    const float* Whh = (const float*)d_in[2];
    const float* bih = (const float*)d_in[3];
    const float* bhh = (const float*)d_in[4];
    const float* W1  = (const float*)d_in[5];
    const float* b1  = (const float*)d_in[6];
    const float* W2  = (const float*)d_in[7];
    const float* b2  = (const float*)d_in[8];
    const float* W3  = (const float*)d_in[9];
    const float* b3  = (const float*)d_in[10];
    float* out = (float*)d_out;

    unsigned short* gxb = (unsigned short*)d_ws;                   // 33.55 MB bf16
    float* hc = (float*)((char*)d_ws + (size_t)TC * GX_PER_T * 2); // 256 KB h+c

    for (int c = 0; c < NCHUNK; ++c) {
        gemm_gx_kernel<<<dim3(2 * TC, 4), 256, 0, stream>>>(x, Wih, bih, bhh, gxb, c * TC);
        lstm_mfma_kernel<<<dim3(NBLK), 512, 0, stream>>>(gxb, Whh, hc, c == 0);
    }
    head_kernel<<<dim3(BATCH), 64, 0, stream>>>(hc, W1, b1, W2, b2, W3, b3, out);
}